// Round 2
// baseline (1681.760 us; speedup 1.0000x reference)
//
#include <hip/hip_runtime.h>
#include <math.h>

typedef __attribute__((ext_vector_type(8))) short bf16x8;
typedef __attribute__((ext_vector_type(4))) float f32x4;

#define TM 19
#define NV 30000
#define NB 96   // persistent blocks (<=256 CUs -> co-resident)

__device__ __forceinline__ float bf2f(unsigned short u){
  union { unsigned int i; float f; } v; v.i = ((unsigned int)u) << 16; return v.f;
}
__device__ __forceinline__ unsigned short f2bf(float f){
  union { float f; unsigned int i; } v; v.f = f;
  unsigned int x = v.i;
  unsigned int r = (x + 0x7fffu + ((x >> 16) & 1u)) >> 16;
  return (unsigned short)r;
}

// ---------------- grid barrier (monotonic counter, agent scope) ----------------
__device__ __forceinline__ void gbar(int* cnt, int& phase){
  __syncthreads();
  if(threadIdx.x == 0){
    phase++;
    __threadfence();  // release: drain this block's stores (incl. L2 writeback)
    __hip_atomic_fetch_add(cnt, 1, __ATOMIC_RELEASE, __HIP_MEMORY_SCOPE_AGENT);
    while(__hip_atomic_load(cnt, __ATOMIC_ACQUIRE, __HIP_MEMORY_SCOPE_AGENT) < NB*phase){
      __builtin_amdgcn_s_sleep(1);
    }
    __threadfence();  // acquire side belt-and-braces
  }
  __syncthreads();
}

// ---------------- sort (stable descending argsort of lengths) ----------------
__global__ void k_sort(const int* __restrict__ lengths, const int* __restrict__ captions,
                       int* __restrict__ sort_ws, int* __restrict__ dl_ws, int* __restrict__ caps_ws,
                       float* __restrict__ out_caps, float* __restrict__ out_dl, float* __restrict__ out_sort,
                       int* __restrict__ cnt){
  int b = threadIdx.x; // 64 threads
  if(b == 0) *cnt = 0;
  __shared__ int len_s[64];
  len_s[b] = lengths[b];
  __syncthreads();
  int lb = len_s[b];
  int r = 0;
  for(int j = 0; j < 64; j++){
    int lj = len_s[j];
    r += (lj > lb) || (lj == lb && j < b);
  }
  sort_ws[r] = b;
  dl_ws[r] = lb - 1;
  out_sort[r] = (float)b;
  out_dl[r] = (float)(lb - 1);
  for(int tt = 0; tt < 20; tt++){
    int c = captions[b*20 + tt];
    caps_ws[r*20 + tt] = c;
    out_caps[r*20 + tt] = (float)c;
  }
}

// ---------------- f32 -> bf16 convert, 4 elems/thread ----------------
__global__ void k_cvt4(const float4* __restrict__ src, ushort4* __restrict__ dst, int n4){
  int i = blockIdx.x*256 + threadIdx.x;
  if(i < n4){
    float4 v = src[i];
    ushort4 o; o.x = f2bf(v.x); o.y = f2bf(v.y); o.z = f2bf(v.z); o.w = f2bf(v.w);
    dst[i] = o;
  }
}

// ---------------- gather+convert sorted features ----------------
__global__ void k_feats(const float* __restrict__ feats, const int* __restrict__ sort_ws,
                        unsigned short* __restrict__ feats_bf){
  int rp = blockIdx.x; // 3136 = r*49+p
  int r = rp / 49, p = rp % 49;
  int sb = sort_ws[r];
  const float* src = feats + ((size_t)sb*49 + p)*1024;
  unsigned short* dst = feats_bf + (size_t)rp*1024;
  int f = threadIdx.x*4;
  float4 v = *(const float4*)(src + f);
  ushort4 o; o.x = f2bf(v.x); o.y = f2bf(v.y); o.z = f2bf(v.z); o.w = f2bf(v.w);
  *(ushort4*)(dst + f) = o;
}

// ---------------- per-batch feature mean (fp32, sorted) ----------------
__global__ void k_featmean(const float* __restrict__ feats, const int* __restrict__ sort_ws,
                           float* __restrict__ fm){
  int r = blockIdx.x;
  int sb = sort_ws[r];
  const float* src = feats + (size_t)sb*49*1024;
  int f = threadIdx.x*4;
  float a0=0,a1=0,a2=0,a3=0;
  for(int p = 0; p < 49; p++){
    float4 v = *(const float4*)(src + p*1024 + f);
    a0 += v.x; a1 += v.y; a2 += v.z; a3 += v.w;
  }
  const float inv = 1.0f/49.0f;
  float4 o; o.x=a0*inv; o.y=a1*inv; o.z=a2*inv; o.w=a3*inv;
  *(float4*)(fm + r*1024 + f) = o;
}

// ---------------- h0 = fmean @ Winit.T + binit ----------------
__global__ void k_h0(const float* __restrict__ fm, const float* __restrict__ Winit,
                     const float* __restrict__ binit,
                     float* __restrict__ h, unsigned short* __restrict__ h_bf){
  int idx = blockIdx.x*256 + threadIdx.x; // 32768 = 64*512
  int r = idx >> 9, n = idx & 511;
  const float* a = fm + r*1024;
  const float* wrow = Winit + (size_t)n*1024;
  float s = 0.f;
  for(int k = 0; k < 1024; k += 4){
    float4 av = *(const float4*)(a + k);
    float4 wv = *(const float4*)(wrow + k);
    s += av.x*wv.x + av.y*wv.y + av.z*wv.z + av.w*wv.w;
  }
  s += binit[n];
  h[idx] = s;
  h_bf[idx] = f2bf(s);
}

// ---------------- embedding gather -> bf16, rows t*64+r ----------------
__global__ void k_embs(const float* __restrict__ emb, const int* __restrict__ caps_ws,
                       unsigned short* __restrict__ embs_bf){
  int row = blockIdx.x; // 1216
  int t = row >> 6, r = row & 63;
  int cap = caps_ws[r*20 + t];
  const float* src = emb + (size_t)cap*512;
  unsigned short* dst = embs_bf + (size_t)row*512;
  int e = threadIdx.x*2;
  float2 v = *(const float2*)(src + e);
  dst[e]   = f2bf(v.x);
  dst[e+1] = f2bf(v.y);
}

// ---------------- 64x64 bf16 MFMA tile, C = A @ B^T (device fn) ----------------
__device__ __forceinline__ void gemm64_dev(
    const unsigned short* __restrict__ A, int lda,
    const unsigned short* __restrict__ B, int ldb,
    float* __restrict__ C, int ldc, int kiters,
    unsigned short* As, unsigned short* Bs){
  int tid = threadIdx.x;
  int wave = tid >> 6, lane = tid & 63;
  int lrow = tid >> 2, lcol = (tid & 3)*8;
  const unsigned short* Ag = A + (size_t)lrow*lda + lcol;
  const unsigned short* Bg = B + (size_t)lrow*ldb + lcol;
  f32x4 acc0 = {0,0,0,0}, acc1 = {0,0,0,0}, acc2 = {0,0,0,0}, acc3 = {0,0,0,0};
  int quad = lane >> 4;
  int mrow = (wave << 4) + (lane & 15);
  for(int it = 0; it < kiters; it++){
    uint4 av = *(const uint4*)(Ag + it*32);
    uint4 bv = *(const uint4*)(Bg + it*32);
    __syncthreads();
    *(uint4*)(&As[lrow*40 + lcol]) = av;
    *(uint4*)(&Bs[lrow*40 + lcol]) = bv;
    __syncthreads();
    bf16x8 a = *(const bf16x8*)(&As[mrow*40 + quad*8]);
    bf16x8 b0 = *(const bf16x8*)(&Bs[( 0 + (lane & 15))*40 + quad*8]);
    bf16x8 b1 = *(const bf16x8*)(&Bs[(16 + (lane & 15))*40 + quad*8]);
    bf16x8 b2 = *(const bf16x8*)(&Bs[(32 + (lane & 15))*40 + quad*8]);
    bf16x8 b3 = *(const bf16x8*)(&Bs[(48 + (lane & 15))*40 + quad*8]);
    acc0 = __builtin_amdgcn_mfma_f32_16x16x32_bf16(a, b0, acc0, 0, 0, 0);
    acc1 = __builtin_amdgcn_mfma_f32_16x16x32_bf16(a, b1, acc1, 0, 0, 0);
    acc2 = __builtin_amdgcn_mfma_f32_16x16x32_bf16(a, b2, acc2, 0, 0, 0);
    acc3 = __builtin_amdgcn_mfma_f32_16x16x32_bf16(a, b3, acc3, 0, 0, 0);
  }
  int col = lane & 15;
  #pragma unroll
  for(int rg = 0; rg < 4; rg++){
    int m = (wave << 4) + quad*4 + rg;
    float* crow = C + (size_t)m*ldc + col;
    crow[0]  = acc0[rg];
    crow[16] = acc1[rg];
    crow[32] = acc2[rg];
    crow[48] = acc3[rg];
  }
}

// ---------------- standalone 64x64 GEMM (preloop, split-K via z) ----------------
__global__ __launch_bounds__(256) void k_gemm64(
    const unsigned short* __restrict__ A, int lda,
    const unsigned short* __restrict__ Bm, int ldb,
    float* __restrict__ C, int ldc, int Ksplit){
  __shared__ unsigned short As[64*40];
  __shared__ unsigned short Bs[64*40];
  int m0 = blockIdx.y*64, n0 = blockIdx.x*64;
  int k0 = blockIdx.z*Ksplit;
  float* Cb = C + (size_t)blockIdx.z * ((size_t)gridDim.y*64*ldc);
  gemm64_dev(A + (size_t)m0*lda + k0, lda, Bm + (size_t)n0*ldb + k0, ldb,
             Cb + (size_t)m0*ldc + n0, ldc, Ksplit/32, As, Bs);
}

// ---------------- persistent recurrence kernel ----------------
__global__ __launch_bounds__(256) void k_loop(
    const float* __restrict__ att1, const float* __restrict__ bd, const float* __restrict__ be,
    const float* __restrict__ Wf, const float* __restrict__ bfb, const float* __restrict__ bbeta,
    const unsigned short* __restrict__ feats_bf, const int* __restrict__ dl_ws,
    const unsigned short* __restrict__ W1_bf, const unsigned short* __restrict__ Wih_bf,
    const float* __restrict__ gi_emb, const float* __restrict__ bih, const float* __restrict__ bhh,
    float* __restrict__ y1p, float* __restrict__ gip,
    unsigned short* __restrict__ xawe_bf,
    float* __restrict__ h, unsigned short* __restrict__ h_bf, unsigned short* __restrict__ hseq,
    float* __restrict__ out_alph, int* cnt){
  __shared__ __align__(16) char smbuf[10240];
  unsigned short* As = (unsigned short*)smbuf;
  unsigned short* Bs = (unsigned short*)(smbuf + 5120);
  float* att2s = (float*)smbuf;           // 512 f
  float* es    = (float*)(smbuf + 2048);  // 64 f
  float* alph  = (float*)(smbuf + 2304);  // 49 f
  int blk = blockIdx.x;
  int tid = threadIdx.x;
  int phase = 0;

  for(int t = 0; t < TM; t++){
    // ---- Phase A: y1 = h @ [Wd;Wbeta;Whh]^T, M=64 N=3072 K=512, 48 tiles x splitK2 ----
    {
      int tile = blk % 48, ks = blk / 48;
      int n0 = tile*64, k0 = ks*256;
      gemm64_dev(h_bf + k0, 512, W1_bf + (size_t)n0*512 + k0, 512,
                 y1p + (size_t)ks*64*3072 + n0, 3072, 8, As, Bs);
    }
    gbar(cnt, phase);

    // ---- Phase B: attention + softmax + awe + gate -> x_awe (blocks 0..63) ----
    if(blk < 64){
      int r = blk;
      int wave = tid >> 6, lane = tid & 63;
      const float* y0 = y1p + (size_t)r*3072;
      const float* y1 = y1p + (size_t)64*3072 + (size_t)r*3072;
      for(int k = tid; k < 512; k += 256) att2s[k] = y0[k] + y1[k] + bd[k] + be[k];
      __syncthreads();
      for(int p = wave; p < 49; p += 4){
        const float* arow = att1 + ((size_t)r*49 + p)*512;
        float s = 0.f;
        #pragma unroll
        for(int i = 0; i < 8; i++){
          int k = lane + i*64;
          float v = arow[k] + att2s[k];
          s += fmaxf(v, 0.f) * Wf[k];
        }
        #pragma unroll
        for(int off = 32; off; off >>= 1) s += __shfl_xor(s, off, 64);
        if(lane == 0) es[p] = s + bfb[0];
      }
      __syncthreads();
      if(wave == 0){
        float v = (lane < 49) ? es[lane] : -1e30f;
        float m = v;
        #pragma unroll
        for(int off = 32; off; off >>= 1) m = fmaxf(m, __shfl_xor(m, off, 64));
        float ex = (lane < 49) ? __expf(v - m) : 0.f;
        float sm = ex;
        #pragma unroll
        for(int off = 32; off; off >>= 1) sm += __shfl_xor(sm, off, 64);
        float al = ex / sm;
        if(lane < 49){
          alph[lane] = al;
          bool act = t < dl_ws[r];
          out_alph[(size_t)r*(TM*49) + t*49 + lane] = act ? al : 0.f;
        }
      }
      __syncthreads();
      int f0 = tid*4;
      float a0=0,a1=0,a2=0,a3=0;
      const unsigned short* fr = feats_bf + (size_t)r*49*1024 + f0;
      for(int p = 0; p < 49; p++){
        float al = alph[p];
        ushort4 v = *(const ushort4*)(fr + p*1024);
        a0 += al*bf2f(v.x); a1 += al*bf2f(v.y); a2 += al*bf2f(v.z); a3 += al*bf2f(v.w);
      }
      const float* g0 = y0 + 512;
      const float* g1 = y1 + 512;
      ushort4 xo;
      float gp;
      gp = g0[f0+0] + g1[f0+0] + bbeta[f0+0]; xo.x = f2bf(a0 / (1.f + __expf(-gp)));
      gp = g0[f0+1] + g1[f0+1] + bbeta[f0+1]; xo.y = f2bf(a1 / (1.f + __expf(-gp)));
      gp = g0[f0+2] + g1[f0+2] + bbeta[f0+2]; xo.z = f2bf(a2 / (1.f + __expf(-gp)));
      gp = g0[f0+3] + g1[f0+3] + bbeta[f0+3]; xo.w = f2bf(a3 / (1.f + __expf(-gp)));
      *(ushort4*)(xawe_bf + (size_t)r*1024 + f0) = xo;
    }
    gbar(cnt, phase);

    // ---- Phase C: gi_awe = x_awe @ Wih[:,512:]^T, M=64 N=1536 K=1024, 24 tiles x splitK4 ----
    {
      int tile = blk % 24, ks = blk / 24;
      int n0 = tile*64, k0 = ks*256;
      gemm64_dev(xawe_bf + k0, 1024, Wih_bf + 512 + (size_t)n0*1536 + k0, 1536,
                 gip + (size_t)ks*64*1536 + n0, 1536, 8, As, Bs);
    }
    gbar(cnt, phase);

    // ---- Phase D: GRU elementwise ----
    for(int idx = blk*256 + tid; idx < 32768; idx += NB*256){
      int r = idx >> 9, j = idx & 511;
      const float* ge = gi_emb + (size_t)(t*64 + r)*1536;
      float ir = ge[j], iz = ge[512 + j], in_ = ge[1024 + j];
      #pragma unroll
      for(int s = 0; s < 4; s++){
        const float* gp = gip + (size_t)s*64*1536 + (size_t)r*1536;
        ir += gp[j]; iz += gp[512 + j]; in_ += gp[1024 + j];
      }
      ir += bih[j]; iz += bih[512 + j]; in_ += bih[1024 + j];
      float hr = bhh[j], hz = bhh[512 + j], hn = bhh[1024 + j];
      #pragma unroll
      for(int s = 0; s < 2; s++){
        const float* yp = y1p + (size_t)s*64*3072 + (size_t)r*3072 + 1536;
        hr += yp[j]; hz += yp[512 + j]; hn += yp[1024 + j];
      }
      float rg = 1.f / (1.f + __expf(-(ir + hr)));
      float zg = 1.f / (1.f + __expf(-(iz + hz)));
      float ng = tanhf(in_ + rg*hn);
      float hold = h[idx];
      float hnew = (1.f - zg)*ng + zg*hold;
      hseq[(size_t)t*32768 + idx] = f2bf(hnew);
      bool act = t < dl_ws[r];
      float hout = act ? hnew : hold;
      h[idx] = hout;
      h_bf[idx] = f2bf(hout);
    }
    gbar(cnt, phase);
  }
}

// ---------------- final vocab projection: (1216x512)@(512x30000)^T + mask ----------------
// grid: x = m-tile (19, fastest -> 19 blocks share one Wfc tile), y = n-tile (469)
__global__ __launch_bounds__(256) void k_preds(
    const unsigned short* __restrict__ hseq, const unsigned short* __restrict__ Wfc_bf,
    const float* __restrict__ bfc, const int* __restrict__ dl_ws,
    float* __restrict__ out_pred){
  __shared__ unsigned short As[64*40];
  __shared__ unsigned short Bs[64*40];
  int tid = threadIdx.x;
  int wave = tid >> 6, lane = tid & 63;
  int m0 = blockIdx.x*64, n0 = blockIdx.y*64;
  int lrow = tid >> 2, lcol = (tid & 3)*8;
  const unsigned short* Ag = hseq + (size_t)(m0 + lrow)*512 + lcol;
  int brow = n0 + lrow;
  bool bvalid = brow < NV;
  const unsigned short* Bg = Wfc_bf + (size_t)(bvalid ? brow : 0)*512 + lcol;
  f32x4 acc0 = {0,0,0,0}, acc1 = {0,0,0,0}, acc2 = {0,0,0,0}, acc3 = {0,0,0,0};
  int quad = lane >> 4;
  int mrow = (wave << 4) + (lane & 15);
  for(int kk = 0; kk < 512; kk += 32){
    uint4 av = *(const uint4*)(Ag + kk);
    uint4 bv;
    if(bvalid) bv = *(const uint4*)(Bg + kk);
    else { bv.x = 0; bv.y = 0; bv.z = 0; bv.w = 0; }
    __syncthreads();
    *(uint4*)(&As[lrow*40 + lcol]) = av;
    *(uint4*)(&Bs[lrow*40 + lcol]) = bv;
    __syncthreads();
    bf16x8 a = *(const bf16x8*)(&As[mrow*40 + quad*8]);
    bf16x8 b0 = *(const bf16x8*)(&Bs[( 0 + (lane & 15))*40 + quad*8]);
    bf16x8 b1 = *(const bf16x8*)(&Bs[(16 + (lane & 15))*40 + quad*8]);
    bf16x8 b2 = *(const bf16x8*)(&Bs[(32 + (lane & 15))*40 + quad*8]);
    bf16x8 b3 = *(const bf16x8*)(&Bs[(48 + (lane & 15))*40 + quad*8]);
    acc0 = __builtin_amdgcn_mfma_f32_16x16x32_bf16(a, b0, acc0, 0, 0, 0);
    acc1 = __builtin_amdgcn_mfma_f32_16x16x32_bf16(a, b1, acc1, 0, 0, 0);
    acc2 = __builtin_amdgcn_mfma_f32_16x16x32_bf16(a, b2, acc2, 0, 0, 0);
    acc3 = __builtin_amdgcn_mfma_f32_16x16x32_bf16(a, b3, acc3, 0, 0, 0);
  }
  int col = lane & 15;
  #pragma unroll
  for(int j = 0; j < 4; j++){
    int n = n0 + j*16 + col;
    if(n < NV){
      float bias = bfc[n];
      f32x4 acc = (j == 0) ? acc0 : (j == 1) ? acc1 : (j == 2) ? acc2 : acc3;
      #pragma unroll
      for(int rg = 0; rg < 4; rg++){
        int mr = m0 + (wave << 4) + quad*4 + rg;
        int t = mr >> 6, r = mr & 63;
        bool act = t < dl_ws[r];
        float v = act ? (acc[rg] + bias) : 0.f;
        out_pred[(size_t)r*((size_t)TM*NV) + (size_t)t*NV + n] = v;
      }
    }
  }
}

extern "C" void kernel_launch(void* const* d_in, const int* in_sizes, int n_in,
                              void* d_out, int out_size, void* d_ws, size_t ws_size,
                              hipStream_t stream){
  const float* features = (const float*)d_in[0];
  const int*   captions = (const int*)d_in[1];
  const int*   lengths  = (const int*)d_in[2];
  const float* We    = (const float*)d_in[3];
  const float* be    = (const float*)d_in[4];
  const float* Wd    = (const float*)d_in[5];
  const float* bd    = (const float*)d_in[6];
  const float* Wf    = (const float*)d_in[7];
  const float* bfb   = (const float*)d_in[8];
  const float* emb   = (const float*)d_in[9];
  const float* Wih   = (const float*)d_in[10];
  const float* Whh   = (const float*)d_in[11];
  const float* bih   = (const float*)d_in[12];
  const float* bhh   = (const float*)d_in[13];
  const float* Winit = (const float*)d_in[14];
  const float* binit = (const float*)d_in[15];
  const float* Wbeta = (const float*)d_in[16];
  const float* bbeta = (const float*)d_in[17];
  const float* Wfc   = (const float*)d_in[18];
  const float* bfc   = (const float*)d_in[19];

  float* out = (float*)d_out;
  float* out_pred = out;                 // 36,480,000
  float* out_caps = out + 36480000;      // 1,280
  float* out_dl   = out + 36481280;      // 64
  float* out_alph = out + 36481344;      // 59,584
  float* out_sort = out + 36540928;      // 64

  char* w = (char*)d_ws;
  auto alloc = [&](size_t bytes){ void* p = (void*)w; w += (bytes + 255) & ~(size_t)255; return p; };
  unsigned short* We_bf    = (unsigned short*)alloc((size_t)512*1024*2);
  unsigned short* W1_bf    = (unsigned short*)alloc((size_t)3072*512*2);   // [Wd;Wbeta;Whh]
  unsigned short* Wih_bf   = (unsigned short*)alloc((size_t)1536*1536*2);
  unsigned short* Wfc_bf   = (unsigned short*)alloc((size_t)NV*512*2);
  unsigned short* feats_bf = (unsigned short*)alloc((size_t)64*49*1024*2);
  unsigned short* embs_bf  = (unsigned short*)alloc((size_t)1216*512*2);
  unsigned short* hseq_bf  = (unsigned short*)alloc((size_t)1216*512*2);
  unsigned short* h_bf     = (unsigned short*)alloc((size_t)64*512*2);
  unsigned short* xawe_bf  = (unsigned short*)alloc((size_t)64*1024*2);
  float* att1   = (float*)alloc((size_t)3136*512*4);
  float* gi_emb = (float*)alloc((size_t)1216*1536*4);
  float* y1p    = (float*)alloc((size_t)2*64*3072*4);
  float* gip    = (float*)alloc((size_t)4*64*1536*4);
  float* hbuf   = (float*)alloc((size_t)64*512*4);
  float* fmean  = (float*)alloc((size_t)64*1024*4);
  int* sort_ws  = (int*)alloc(64*4);
  int* dl_ws    = (int*)alloc(64*4);
  int* caps_ws  = (int*)alloc(1280*4);
  int* cnt      = (int*)alloc(256);
  (void)in_sizes; (void)n_in; (void)out_size; (void)ws_size;

  k_sort<<<1, 64, 0, stream>>>(lengths, captions, sort_ws, dl_ws, caps_ws, out_caps, out_dl, out_sort, cnt);

  k_cvt4<<<512,  256, 0, stream>>>((const float4*)We,    (ushort4*)We_bf,             512*1024/4);
  k_cvt4<<<256,  256, 0, stream>>>((const float4*)Wd,    (ushort4*)W1_bf,             512*512/4);
  k_cvt4<<<512,  256, 0, stream>>>((const float4*)Wbeta, (ushort4*)(W1_bf + 512*512), 1024*512/4);
  k_cvt4<<<768,  256, 0, stream>>>((const float4*)Whh,   (ushort4*)(W1_bf + 1536*512),1536*512/4);
  k_cvt4<<<2304, 256, 0, stream>>>((const float4*)Wih,   (ushort4*)Wih_bf,            1536*1536/4);
  k_cvt4<<<15000,256, 0, stream>>>((const float4*)Wfc,   (ushort4*)Wfc_bf,            NV*512/4);

  k_feats<<<3136, 256, 0, stream>>>(features, sort_ws, feats_bf);
  k_featmean<<<64, 256, 0, stream>>>(features, sort_ws, fmean);
  k_h0<<<128, 256, 0, stream>>>(fmean, Winit, binit, hbuf, h_bf);
  k_embs<<<1216, 256, 0, stream>>>(emb, caps_ws, embs_bf);

  // att1 = feats_s @ We^T : M=3136, N=512, K=1024
  k_gemm64<<<dim3(8, 49, 1), 256, 0, stream>>>(feats_bf, 1024, We_bf, 1024, att1, 512, 1024);
  // gi_emb = embs @ Wih[:, :512]^T : M=1216, N=1536, K=512
  k_gemm64<<<dim3(24, 19, 1), 256, 0, stream>>>(embs_bf, 512, Wih_bf, 1536, gi_emb, 1536, 512);

  // full recurrence in one persistent launch
  k_loop<<<NB, 256, 0, stream>>>(att1, bd, be, Wf, bfb, bbeta, feats_bf, dl_ws,
                                 W1_bf, Wih_bf, gi_emb, bih, bhh,
                                 y1p, gip, xawe_bf, hbuf, h_bf, hseq_bf, out_alph, cnt);

  // predictions: (1216 x 512) @ (512 x 30000)^T, masked scatter to out
  k_preds<<<dim3(19, 469, 1), 256, 0, stream>>>(hseq_bf, Wfc_bf, bfc, dl_ws, out_pred);
}

// Round 3
// 1343.661 us; speedup vs baseline: 1.2516x; 1.2516x over previous
//
#include <hip/hip_runtime.h>
#include <math.h>

typedef __attribute__((ext_vector_type(8))) short bf16x8;
typedef __attribute__((ext_vector_type(4))) float f32x4;

#define TM 19
#define NV 30000
#define NB 96   // persistent blocks (<=256 CUs -> co-resident; verified resident in R2)

__device__ __forceinline__ float bf2f(unsigned short u){
  union { unsigned int i; float f; } v; v.i = ((unsigned int)u) << 16; return v.f;
}
__device__ __forceinline__ unsigned short f2bf(float f){
  union { float f; unsigned int i; } v; v.f = f;
  unsigned int x = v.i;
  unsigned int r = (x + 0x7fffu + ((x >> 16) & 1u)) >> 16;
  return (unsigned short)r;
}

// ---- relaxed agent-scope (sc1 -> LLC-coherent) load/store helpers ----
__device__ __forceinline__ float ald_f(const float* p){
  return __hip_atomic_load(p, __ATOMIC_RELAXED, __HIP_MEMORY_SCOPE_AGENT);
}
__device__ __forceinline__ void ast_f(float* p, float v){
  __hip_atomic_store(p, v, __ATOMIC_RELAXED, __HIP_MEMORY_SCOPE_AGENT);
}
__device__ __forceinline__ float2 ald_f2(const float* p){
  unsigned long long u = __hip_atomic_load((const unsigned long long*)p, __ATOMIC_RELAXED, __HIP_MEMORY_SCOPE_AGENT);
  union { unsigned long long u; float2 f; } c; c.u = u; return c.f;
}
__device__ __forceinline__ unsigned long long ald_u64(const void* p){
  return __hip_atomic_load((const unsigned long long*)p, __ATOMIC_RELAXED, __HIP_MEMORY_SCOPE_AGENT);
}
__device__ __forceinline__ void ast_u64(void* p, unsigned long long v){
  __hip_atomic_store((unsigned long long*)p, v, __ATOMIC_RELAXED, __HIP_MEMORY_SCOPE_AGENT);
}
__device__ __forceinline__ void ast_u32(void* p, unsigned int v){
  __hip_atomic_store((unsigned int*)p, v, __ATOMIC_RELAXED, __HIP_MEMORY_SCOPE_AGENT);
}

// ---------------- cheap grid barrier: no fences, no L2 flush ----------------
// Sound because: (1) __syncthreads drains each thread's vmcnt (stores at LLC for
// sc1 data); (2) flag add/spin are sc1 atomics at the same coherence point.
__device__ __forceinline__ void gbar(int* cnt, int& phase){
  __syncthreads();
  if(threadIdx.x == 0){
    phase++;
    asm volatile("s_waitcnt vmcnt(0)" ::: "memory");
    __hip_atomic_fetch_add(cnt, 1, __ATOMIC_RELAXED, __HIP_MEMORY_SCOPE_AGENT);
    while(__hip_atomic_load(cnt, __ATOMIC_RELAXED, __HIP_MEMORY_SCOPE_AGENT) < NB*phase){
      __builtin_amdgcn_s_sleep(1);
    }
  }
  __syncthreads();
}

// ---------------- sort (stable descending argsort of lengths) ----------------
__global__ void k_sort(const int* __restrict__ lengths, const int* __restrict__ captions,
                       int* __restrict__ sort_ws, int* __restrict__ dl_ws, int* __restrict__ caps_ws,
                       float* __restrict__ out_caps, float* __restrict__ out_dl, float* __restrict__ out_sort,
                       int* __restrict__ cnt){
  int b = threadIdx.x; // 64 threads
  if(b == 0) *cnt = 0;
  __shared__ int len_s[64];
  len_s[b] = lengths[b];
  __syncthreads();
  int lb = len_s[b];
  int r = 0;
  for(int j = 0; j < 64; j++){
    int lj = len_s[j];
    r += (lj > lb) || (lj == lb && j < b);
  }
  sort_ws[r] = b;
  dl_ws[r] = lb - 1;
  out_sort[r] = (float)b;
  out_dl[r] = (float)(lb - 1);
  for(int tt = 0; tt < 20; tt++){
    int c = captions[b*20 + tt];
    caps_ws[r*20 + tt] = c;
    out_caps[r*20 + tt] = (float)c;
  }
}

// ---------------- all loop-weight converts in ONE kernel ----------------
__global__ void k_cvtW(const float* __restrict__ We, const float* __restrict__ Wd,
                       const float* __restrict__ Wbeta, const float* __restrict__ Whh,
                       const float* __restrict__ Wih,
                       unsigned short* __restrict__ We_bf, unsigned short* __restrict__ W1_bf,
                       unsigned short* __restrict__ Wih_bf){
  int i = blockIdx.x*256 + threadIdx.x;  // 4352*256 = 1,114,112 float4s exactly
  const float4* s; ushort4* d;
  if(i < 131072)      { s = (const float4*)We    + i;            d = (ushort4*)We_bf  + i; }
  else if(i < 196608) { int j = i-131072; s = (const float4*)Wd    + j; d = (ushort4*)W1_bf  + j; }
  else if(i < 327680) { int j = i-196608; s = (const float4*)Wbeta + j; d = (ushort4*)W1_bf  + 65536 + j; }
  else if(i < 524288) { int j = i-327680; s = (const float4*)Whh   + j; d = (ushort4*)W1_bf  + 196608 + j; }
  else                { int j = i-524288; s = (const float4*)Wih   + j; d = (ushort4*)Wih_bf + j; }
  float4 v = *s;
  ushort4 o; o.x = f2bf(v.x); o.y = f2bf(v.y); o.z = f2bf(v.z); o.w = f2bf(v.w);
  *d = o;
}

// ---------------- gather+convert sorted features ----------------
__global__ void k_feats(const float* __restrict__ feats, const int* __restrict__ sort_ws,
                        unsigned short* __restrict__ feats_bf){
  int rp = blockIdx.x; // 3136 = r*49+p
  int r = rp / 49, p = rp % 49;
  int sb = sort_ws[r];
  const float* src = feats + ((size_t)sb*49 + p)*1024;
  unsigned short* dst = feats_bf + (size_t)rp*1024;
  int f = threadIdx.x*4;
  float4 v = *(const float4*)(src + f);
  ushort4 o; o.x = f2bf(v.x); o.y = f2bf(v.y); o.z = f2bf(v.z); o.w = f2bf(v.w);
  *(ushort4*)(dst + f) = o;
}

// ---------------- per-batch feature mean ----------------
__global__ void k_featmean(const float* __restrict__ feats, const int* __restrict__ sort_ws,
                           float* __restrict__ fm){
  int r = blockIdx.x;
  int sb = sort_ws[r];
  const float* src = feats + (size_t)sb*49*1024;
  int f = threadIdx.x*4;
  float a0=0,a1=0,a2=0,a3=0;
  for(int p = 0; p < 49; p++){
    float4 v = *(const float4*)(src + p*1024 + f);
    a0 += v.x; a1 += v.y; a2 += v.z; a3 += v.w;
  }
  const float inv = 1.0f/49.0f;
  float4 o; o.x=a0*inv; o.y=a1*inv; o.z=a2*inv; o.w=a3*inv;
  *(float4*)(fm + r*1024 + f) = o;
}

// ---------------- h0 = fmean @ Winit.T + binit ----------------
__global__ void k_h0(const float* __restrict__ fm, const float* __restrict__ Winit,
                     const float* __restrict__ binit,
                     float* __restrict__ h, unsigned short* __restrict__ h_bf){
  int idx = blockIdx.x*256 + threadIdx.x; // 32768 = 64*512
  int r = idx >> 9, n = idx & 511;
  const float* a = fm + r*1024;
  const float* wrow = Winit + (size_t)n*1024;
  float s = 0.f;
  for(int k = 0; k < 1024; k += 4){
    float4 av = *(const float4*)(a + k);
    float4 wv = *(const float4*)(wrow + k);
    s += av.x*wv.x + av.y*wv.y + av.z*wv.z + av.w*wv.w;
  }
  s += binit[n];
  h[idx] = s;
  h_bf[idx] = f2bf(s);
}

// ---------------- embedding gather -> bf16, rows t*64+r ----------------
__global__ void k_embs(const float* __restrict__ emb, const int* __restrict__ caps_ws,
                       unsigned short* __restrict__ embs_bf){
  int row = blockIdx.x; // 1216
  int t = row >> 6, r = row & 63;
  int cap = caps_ws[r*20 + t];
  const float* src = emb + (size_t)cap*512;
  unsigned short* dst = embs_bf + (size_t)row*512;
  int e = threadIdx.x*2;
  float2 v = *(const float2*)(src + e);
  dst[e]   = f2bf(v.x);
  dst[e+1] = f2bf(v.y);
}

// ---------------- 64x64 bf16 MFMA tile, C = A @ B^T (device fn) ----------------
// AT_A: load A-tile via sc1 atomics (data produced by other blocks this launch)
// AT_C: store C via sc1 atomics (data consumed by other blocks this launch)
template<bool AT_A, bool AT_C>
__device__ __forceinline__ void gemm64_dev(
    const unsigned short* __restrict__ A, int lda,
    const unsigned short* __restrict__ B, int ldb,
    float* __restrict__ C, int ldc, int kiters,
    unsigned short* As, unsigned short* Bs){
  int tid = threadIdx.x;
  int wave = tid >> 6, lane = tid & 63;
  int lrow = tid >> 2, lcol = (tid & 3)*8;
  const unsigned short* Ag = A + (size_t)lrow*lda + lcol;
  const unsigned short* Bg = B + (size_t)lrow*ldb + lcol;
  f32x4 acc0 = {0,0,0,0}, acc1 = {0,0,0,0}, acc2 = {0,0,0,0}, acc3 = {0,0,0,0};
  int quad = lane >> 4;
  int mrow = (wave << 4) + (lane & 15);
  for(int it = 0; it < kiters; it++){
    uint4 av, bv;
    if(AT_A){
      unsigned long long lo = ald_u64(Ag + it*32);
      unsigned long long hi = ald_u64(Ag + it*32 + 4);
      av.x = (unsigned int)lo; av.y = (unsigned int)(lo >> 32);
      av.z = (unsigned int)hi; av.w = (unsigned int)(hi >> 32);
    } else {
      av = *(const uint4*)(Ag + it*32);
    }
    bv = *(const uint4*)(Bg + it*32);
    __syncthreads();
    *(uint4*)(&As[lrow*40 + lcol]) = av;
    *(uint4*)(&Bs[lrow*40 + lcol]) = bv;
    __syncthreads();
    bf16x8 a = *(const bf16x8*)(&As[mrow*40 + quad*8]);
    bf16x8 b0 = *(const bf16x8*)(&Bs[( 0 + (lane & 15))*40 + quad*8]);
    bf16x8 b1 = *(const bf16x8*)(&Bs[(16 + (lane & 15))*40 + quad*8]);
    bf16x8 b2 = *(const bf16x8*)(&Bs[(32 + (lane & 15))*40 + quad*8]);
    bf16x8 b3 = *(const bf16x8*)(&Bs[(48 + (lane & 15))*40 + quad*8]);
    acc0 = __builtin_amdgcn_mfma_f32_16x16x32_bf16(a, b0, acc0, 0, 0, 0);
    acc1 = __builtin_amdgcn_mfma_f32_16x16x32_bf16(a, b1, acc1, 0, 0, 0);
    acc2 = __builtin_amdgcn_mfma_f32_16x16x32_bf16(a, b2, acc2, 0, 0, 0);
    acc3 = __builtin_amdgcn_mfma_f32_16x16x32_bf16(a, b3, acc3, 0, 0, 0);
  }
  int col = lane & 15;
  #pragma unroll
  for(int rg = 0; rg < 4; rg++){
    int m = (wave << 4) + quad*4 + rg;
    float* crow = C + (size_t)m*ldc + col;
    if(AT_C){
      ast_f(crow +  0, acc0[rg]);
      ast_f(crow + 16, acc1[rg]);
      ast_f(crow + 32, acc2[rg]);
      ast_f(crow + 48, acc3[rg]);
    } else {
      crow[0]  = acc0[rg];
      crow[16] = acc1[rg];
      crow[32] = acc2[rg];
      crow[48] = acc3[rg];
    }
  }
}

// ---------------- standalone 64x64 GEMM (preloop) ----------------
__global__ __launch_bounds__(256) void k_gemm64(
    const unsigned short* __restrict__ A, int lda,
    const unsigned short* __restrict__ Bm, int ldb,
    float* __restrict__ C, int ldc, int Ksplit){
  __shared__ unsigned short As[64*40];
  __shared__ unsigned short Bs[64*40];
  int m0 = blockIdx.y*64, n0 = blockIdx.x*64;
  int k0 = blockIdx.z*Ksplit;
  float* Cb = C + (size_t)blockIdx.z * ((size_t)gridDim.y*64*ldc);
  gemm64_dev<false,false>(A + (size_t)m0*lda + k0, lda, Bm + (size_t)n0*ldb + k0, ldb,
                          Cb + (size_t)m0*ldc + n0, ldc, Ksplit/32, As, Bs);
}

// ---------------- persistent recurrence kernel ----------------
__global__ __launch_bounds__(256) void k_loop(
    const float* __restrict__ att1, const float* __restrict__ bd, const float* __restrict__ be,
    const float* __restrict__ Wf, const float* __restrict__ bfb, const float* __restrict__ bbeta,
    const unsigned short* __restrict__ feats_bf, const int* __restrict__ dl_ws,
    const unsigned short* __restrict__ W1_bf, const unsigned short* __restrict__ Wih_bf,
    const float* __restrict__ gi_emb, const float* __restrict__ bih, const float* __restrict__ bhh,
    float* __restrict__ y1p, float* __restrict__ gip,
    unsigned short* __restrict__ xawe_bf,
    float* __restrict__ h, unsigned short* __restrict__ h_bf, unsigned short* __restrict__ hseq,
    float* __restrict__ out_alph, int* cnt){
  __shared__ __align__(16) char smbuf[10240];
  unsigned short* As = (unsigned short*)smbuf;
  unsigned short* Bs = (unsigned short*)(smbuf + 5120);
  float* att2s = (float*)smbuf;           // 512 f
  float* es    = (float*)(smbuf + 2048);  // 64 f
  float* alph  = (float*)(smbuf + 2304);  // 49 f
  int blk = blockIdx.x;
  int tid = threadIdx.x;
  int phase = 0;

  for(int t = 0; t < TM; t++){
    // ---- Phase A: y1 = h @ [Wd;Wbeta;Whh]^T, M=64 N=3072 K=512, 48 tiles x splitK2 ----
    {
      int tile = blk % 48, ks = blk / 48;
      int n0 = tile*64, k0 = ks*256;
      gemm64_dev<true,true>(h_bf + k0, 512, W1_bf + (size_t)n0*512 + k0, 512,
                            y1p + (size_t)ks*64*3072 + n0, 3072, 8, As, Bs);
    }
    gbar(cnt, phase);

    // ---- Phase B: attention + softmax + awe + gate -> x_awe (blocks 0..63) ----
    if(blk < 64){
      int r = blk;
      int wave = tid >> 6, lane = tid & 63;
      const float* y0 = y1p + (size_t)r*3072;
      const float* y1 = y1p + (size_t)64*3072 + (size_t)r*3072;
      {
        int k = tid*2;
        float2 va = ald_f2(y0 + k);
        float2 vb = ald_f2(y1 + k);
        att2s[k]   = va.x + vb.x + bd[k]   + be[k];
        att2s[k+1] = va.y + vb.y + bd[k+1] + be[k+1];
      }
      __syncthreads();
      for(int p = wave; p < 49; p += 4){
        const float* arow = att1 + ((size_t)r*49 + p)*512;
        float s = 0.f;
        #pragma unroll
        for(int i = 0; i < 8; i++){
          int k = lane + i*64;
          float v = arow[k] + att2s[k];
          s += fmaxf(v, 0.f) * Wf[k];
        }
        #pragma unroll
        for(int off = 32; off; off >>= 1) s += __shfl_xor(s, off, 64);
        if(lane == 0) es[p] = s + bfb[0];
      }
      __syncthreads();
      if(wave == 0){
        float v = (lane < 49) ? es[lane] : -1e30f;
        float m = v;
        #pragma unroll
        for(int off = 32; off; off >>= 1) m = fmaxf(m, __shfl_xor(m, off, 64));
        float ex = (lane < 49) ? __expf(v - m) : 0.f;
        float sm = ex;
        #pragma unroll
        for(int off = 32; off; off >>= 1) sm += __shfl_xor(sm, off, 64);
        float al = ex / sm;
        if(lane < 49){
          alph[lane] = al;
          bool act = t < dl_ws[r];
          out_alph[(size_t)r*(TM*49) + t*49 + lane] = act ? al : 0.f;
        }
      }
      __syncthreads();
      int f0 = tid*4;
      float a0=0,a1=0,a2=0,a3=0;
      const unsigned short* fr = feats_bf + (size_t)r*49*1024 + f0;
      for(int p = 0; p < 49; p++){
        float al = alph[p];
        ushort4 v = *(const ushort4*)(fr + p*1024);
        a0 += al*bf2f(v.x); a1 += al*bf2f(v.y); a2 += al*bf2f(v.z); a3 += al*bf2f(v.w);
      }
      float2 g0a = ald_f2(y0 + 512 + f0), g0b = ald_f2(y0 + 512 + f0 + 2);
      float2 g1a = ald_f2(y1 + 512 + f0), g1b = ald_f2(y1 + 512 + f0 + 2);
      float gp;
      unsigned int lo, hi;
      gp = g0a.x + g1a.x + bbeta[f0+0]; lo  = (unsigned int)f2bf(a0 / (1.f + __expf(-gp)));
      gp = g0a.y + g1a.y + bbeta[f0+1]; lo |= (unsigned int)f2bf(a1 / (1.f + __expf(-gp))) << 16;
      gp = g0b.x + g1b.x + bbeta[f0+2]; hi  = (unsigned int)f2bf(a2 / (1.f + __expf(-gp)));
      gp = g0b.y + g1b.y + bbeta[f0+3]; hi |= (unsigned int)f2bf(a3 / (1.f + __expf(-gp))) << 16;
      ast_u64(xawe_bf + (size_t)r*1024 + f0, ((unsigned long long)hi << 32) | lo);
    }
    gbar(cnt, phase);

    // ---- Phase C: gi_awe = x_awe @ Wih[:,512:]^T, M=64 N=1536 K=1024, 24 tiles x splitK4 ----
    {
      int tile = blk % 24, ks = blk / 24;
      int n0 = tile*64, k0 = ks*256;
      gemm64_dev<true,true>(xawe_bf + k0, 1024, Wih_bf + 512 + (size_t)n0*1536 + k0, 1536,
                            gip + (size_t)ks*64*1536 + n0, 1536, 8, As, Bs);
    }
    gbar(cnt, phase);

    // ---- Phase D: GRU elementwise, 2 adjacent j per thread ----
    {
      int base = blk*512 + tid*2;
      if(base < 32768){
        int r = base >> 9, j = base & 511;
        const float* ge = gi_emb + (size_t)(t*64 + r)*1536;
        float2 e0 = *(const float2*)(ge + j);
        float2 e1 = *(const float2*)(ge + 512 + j);
        float2 e2 = *(const float2*)(ge + 1024 + j);
        float ir0 = e0.x, ir1 = e0.y, iz0 = e1.x, iz1 = e1.y, in0 = e2.x, in1 = e2.y;
        #pragma unroll
        for(int s = 0; s < 4; s++){
          const float* gp = gip + (size_t)s*64*1536 + (size_t)r*1536;
          float2 f;
          f = ald_f2(gp + j);        ir0 += f.x; ir1 += f.y;
          f = ald_f2(gp + 512 + j);  iz0 += f.x; iz1 += f.y;
          f = ald_f2(gp + 1024 + j); in0 += f.x; in1 += f.y;
        }
        ir0 += bih[j]; ir1 += bih[j+1];
        iz0 += bih[512+j]; iz1 += bih[512+j+1];
        in0 += bih[1024+j]; in1 += bih[1024+j+1];
        float hr0 = bhh[j], hr1 = bhh[j+1];
        float hz0 = bhh[512+j], hz1 = bhh[512+j+1];
        float hn0 = bhh[1024+j], hn1 = bhh[1024+j+1];
        #pragma unroll
        for(int s = 0; s < 2; s++){
          const float* yp = y1p + (size_t)s*64*3072 + (size_t)r*3072 + 1536;
          float2 f;
          f = ald_f2(yp + j);        hr0 += f.x; hr1 += f.y;
          f = ald_f2(yp + 512 + j);  hz0 += f.x; hz1 += f.y;
          f = ald_f2(yp + 1024 + j); hn0 += f.x; hn1 += f.y;
        }
        float rg0 = 1.f / (1.f + __expf(-(ir0 + hr0)));
        float rg1 = 1.f / (1.f + __expf(-(ir1 + hr1)));
        float zg0 = 1.f / (1.f + __expf(-(iz0 + hz0)));
        float zg1 = 1.f / (1.f + __expf(-(iz1 + hz1)));
        float ng0 = tanhf(in0 + rg0*hn0);
        float ng1 = tanhf(in1 + rg1*hn1);
        float ho0 = h[base], ho1 = h[base+1];
        float hn_0 = (1.f - zg0)*ng0 + zg0*ho0;
        float hn_1 = (1.f - zg1)*ng1 + zg1*ho1;
        *(unsigned int*)(hseq + (size_t)t*32768 + base) =
            (unsigned int)f2bf(hn_0) | ((unsigned int)f2bf(hn_1) << 16);
        bool act = t < dl_ws[r];
        float w0 = act ? hn_0 : ho0;
        float w1 = act ? hn_1 : ho1;
        h[base] = w0; h[base+1] = w1;
        ast_u32(h_bf + base, (unsigned int)f2bf(w0) | ((unsigned int)f2bf(w1) << 16));
      }
    }
    gbar(cnt, phase);
  }
}

// ---------------- final vocab projection, inline f32->bf16 Wfc staging ----------------
// grid: x = m-tile (19, fastest -> consecutive blocks share one Wfc tile), y = n-tile (469)
__global__ __launch_bounds__(256) void k_preds(
    const unsigned short* __restrict__ hseq, const float* __restrict__ Wfc,
    const float* __restrict__ bfc, const int* __restrict__ dl_ws,
    float* __restrict__ out_pred){
  __shared__ unsigned short As[64*40];
  __shared__ unsigned short Bs[64*40];
  int tid = threadIdx.x;
  int wave = tid >> 6, lane = tid & 63;
  int m0 = blockIdx.x*64, n0 = blockIdx.y*64;
  int lrow = tid >> 2, lcol = (tid & 3)*8;
  const unsigned short* Ag = hseq + (size_t)(m0 + lrow)*512 + lcol;
  int brow = n0 + lrow;
  bool bvalid = brow < NV;
  const float* Bg = Wfc + (size_t)(bvalid ? brow : 0)*512 + lcol;
  f32x4 acc0 = {0,0,0,0}, acc1 = {0,0,0,0}, acc2 = {0,0,0,0}, acc3 = {0,0,0,0};
  int quad = lane >> 4;
  int mrow = (wave << 4) + (lane & 15);
  for(int kk = 0; kk < 512; kk += 32){
    uint4 av = *(const uint4*)(Ag + kk);
    uint4 bv;
    if(bvalid){
      float4 f0 = *(const float4*)(Bg + kk);
      float4 f1 = *(const float4*)(Bg + kk + 4);
      bv.x = (unsigned int)f2bf(f0.x) | ((unsigned int)f2bf(f0.y) << 16);
      bv.y = (unsigned int)f2bf(f0.z) | ((unsigned int)f2bf(f0.w) << 16);
      bv.z = (unsigned int)f2bf(f1.x) | ((unsigned int)f2bf(f1.y) << 16);
      bv.w = (unsigned int)f2bf(f1.z) | ((unsigned int)f2bf(f1.w) << 16);
    } else { bv.x = 0; bv.y = 0; bv.z = 0; bv.w = 0; }
    __syncthreads();
    *(uint4*)(&As[lrow*40 + lcol]) = av;
    *(uint4*)(&Bs[lrow*40 + lcol]) = bv;
    __syncthreads();
    bf16x8 a = *(const bf16x8*)(&As[mrow*40 + quad*8]);
    bf16x8 b0 = *(const bf16x8*)(&Bs[( 0 + (lane & 15))*40 + quad*8]);
    bf16x8 b1 = *(const bf16x8*)(&Bs[(16 + (lane & 15))*40 + quad*8]);
    bf16x8 b2 = *(const bf16x8*)(&Bs[(32 + (lane & 15))*40 + quad*8]);
    bf16x8 b3 = *(const bf16x8*)(&Bs[(48 + (lane & 15))*40 + quad*8]);
    acc0 = __builtin_amdgcn_mfma_f32_16x16x32_bf16(a, b0, acc0, 0, 0, 0);
    acc1 = __builtin_amdgcn_mfma_f32_16x16x32_bf16(a, b1, acc1, 0, 0, 0);
    acc2 = __builtin_amdgcn_mfma_f32_16x16x32_bf16(a, b2, acc2, 0, 0, 0);
    acc3 = __builtin_amdgcn_mfma_f32_16x16x32_bf16(a, b3, acc3, 0, 0, 0);
  }
  int col = lane & 15;
  #pragma unroll
  for(int j = 0; j < 4; j++){
    int n = n0 + j*16 + col;
    if(n < NV){
      float bias = bfc[n];
      f32x4 acc = (j == 0) ? acc0 : (j == 1) ? acc1 : (j == 2) ? acc2 : acc3;
      #pragma unroll
      for(int rg = 0; rg < 4; rg++){
        int mr = m0 + (wave << 4) + quad*4 + rg;
        int t = mr >> 6, r = mr & 63;
        bool act = t < dl_ws[r];
        float v = act ? (acc[rg] + bias) : 0.f;
        out_pred[(size_t)r*((size_t)TM*NV) + (size_t)t*NV + n] = v;
      }
    }
  }
}

extern "C" void kernel_launch(void* const* d_in, const int* in_sizes, int n_in,
                              void* d_out, int out_size, void* d_ws, size_t ws_size,
                              hipStream_t stream){
  const float* features = (const float*)d_in[0];
  const int*   captions = (const int*)d_in[1];
  const int*   lengths  = (const int*)d_in[2];
  const float* We    = (const float*)d_in[3];
  const float* be    = (const float*)d_in[4];
  const float* Wd    = (const float*)d_in[5];
  const float* bd    = (const float*)d_in[6];
  const float* Wf    = (const float*)d_in[7];
  const float* bfb   = (const float*)d_in[8];
  const float* emb   = (const float*)d_in[9];
  const float* Wih   = (const float*)d_in[10];
  const float* Whh   = (const float*)d_in[11];
  const float* bih   = (const float*)d_in[12];
  const float* bhh   = (const float*)d_in[13];
  const float* Winit = (const float*)d_in[14];
  const float* binit = (const float*)d_in[15];
  const float* Wbeta = (const float*)d_in[16];
  const float* bbeta = (const float*)d_in[17];
  const float* Wfc   = (const float*)d_in[18];
  const float* bfc   = (const float*)d_in[19];

  float* out = (float*)d_out;
  float* out_pred = out;                 // 36,480,000
  float* out_caps = out + 36480000;      // 1,280
  float* out_dl   = out + 36481280;      // 64
  float* out_alph = out + 36481344;      // 59,584
  float* out_sort = out + 36540928;      // 64

  char* w = (char*)d_ws;
  auto alloc = [&](size_t bytes){ void* p = (void*)w; w += (bytes + 255) & ~(size_t)255; return p; };
  unsigned short* We_bf    = (unsigned short*)alloc((size_t)512*1024*2);
  unsigned short* W1_bf    = (unsigned short*)alloc((size_t)3072*512*2);   // [Wd;Wbeta;Whh]
  unsigned short* Wih_bf   = (unsigned short*)alloc((size_t)1536*1536*2);
  unsigned short* feats_bf = (unsigned short*)alloc((size_t)64*49*1024*2);
  unsigned short* embs_bf  = (unsigned short*)alloc((size_t)1216*512*2);
  unsigned short* hseq_bf  = (unsigned short*)alloc((size_t)1216*512*2);
  unsigned short* h_bf     = (unsigned short*)alloc((size_t)64*512*2);
  unsigned short* xawe_bf  = (unsigned short*)alloc((size_t)64*1024*2);
  float* att1   = (float*)alloc((size_t)3136*512*4);
  float* gi_emb = (float*)alloc((size_t)1216*1536*4);
  float* y1p    = (float*)alloc((size_t)2*64*3072*4);
  float* gip    = (float*)alloc((size_t)4*64*1536*4);
  float* hbuf   = (float*)alloc((size_t)64*512*4);
  float* fmean  = (float*)alloc((size_t)64*1024*4);
  int* sort_ws  = (int*)alloc(64*4);
  int* dl_ws    = (int*)alloc(64*4);
  int* caps_ws  = (int*)alloc(1280*4);
  int* cnt      = (int*)alloc(256);
  (void)in_sizes; (void)n_in; (void)out_size; (void)ws_size;

  k_sort<<<1, 64, 0, stream>>>(lengths, captions, sort_ws, dl_ws, caps_ws, out_caps, out_dl, out_sort, cnt);
  k_cvtW<<<4352, 256, 0, stream>>>(We, Wd, Wbeta, Whh, Wih, We_bf, W1_bf, Wih_bf);
  k_feats<<<3136, 256, 0, stream>>>(features, sort_ws, feats_bf);
  k_featmean<<<64, 256, 0, stream>>>(features, sort_ws, fmean);
  k_h0<<<128, 256, 0, stream>>>(fmean, Winit, binit, hbuf, h_bf);
  k_embs<<<1216, 256, 0, stream>>>(emb, caps_ws, embs_bf);

  // att1 = feats_s @ We^T : M=3136, N=512, K=1024
  k_gemm64<<<dim3(8, 49, 1), 256, 0, stream>>>(feats_bf, 1024, We_bf, 1024, att1, 512, 1024);
  // gi_emb = embs @ Wih[:, :512]^T : M=1216, N=1536, K=512
  k_gemm64<<<dim3(24, 19, 1), 256, 0, stream>>>(embs_bf, 512, Wih_bf, 1536, gi_emb, 1536, 512);

  // full recurrence in one persistent launch (cheap sc1 barriers)
  k_loop<<<NB, 256, 0, stream>>>(att1, bd, be, Wf, bfb, bbeta, feats_bf, dl_ws,
                                 W1_bf, Wih_bf, gi_emb, bih, bhh,
                                 y1p, gip, xawe_bf, hbuf, h_bf, hseq_bf, out_alph, cnt);

  // predictions: (1216 x 512) @ (512 x 30000)^T, masked scatter to out
  k_preds<<<dim3(19, 469, 1), 256, 0, stream>>>(hseq_bf, Wfc, bfc, dl_ws, out_pred);
}